// Round 12
// baseline (364.824 us; speedup 1.0000x reference)
//
#include <hip/hip_runtime.h>
#include <hip/hip_bf16.h>
#include <math.h>

// B=2 S=2048 D=1024 H=16 DH=64 F=4096. ALL inputs/outputs fp32.
// Internals bf16 (MFMA) with fp32 accumulate; residual stream fp32 in d_out.
// Workspace (64 MiB):
//   [0,6)   Wqkv_b  [6,8) Wout_b  [8,16) W1_b  [16,24) W2_b  (contiguous: cvt4)
//   [24,32) h (LN outputs)
//   [32,48) qk [4096][2048] bf16   [48,56) vt [32][64][2048] bf16 V^T
//   [56,64) attn [4096][1024] bf16
//   [32,64) act [4096][4096] bf16 (FFN, aliases qk/vt/attn after attention)
//   x2 fp32 = d_out (out-proj writes; LN2 reads; FFN2 accumulates in place)
//
// Round 12: FFN2 drops split-K — ring-4, 256 blocks (1/CU), NT=128, and a
// plain in-place epilogue (EPI 6: x2 += v + b2, block-exclusive tiles) in
// place of 32 MB of fp32 atomicAdd (an L2 RMW stream; r6 measured +8.8us
// per extra 32 MB of atomics). Ring-4's 2-iteration window is the designed
// latency cover for 1-block/CU. Everything else frozen at r11 (359.6us).

typedef __bf16 bf16;
typedef __bf16 bf16x4 __attribute__((ext_vector_type(4)));
typedef __bf16 bf16x8 __attribute__((ext_vector_type(8)));
typedef float f32x4 __attribute__((ext_vector_type(4)));

#define LOG2E 1.4426950408889634f
#define NSHIFT -17.312340489f   // -12 * log2(e): fixed softmax shift of 12

__device__ __forceinline__ f32x4 mfma16(bf16x8 a, bf16x8 b, f32x4 c) {
    return __builtin_amdgcn_mfma_f32_16x16x32_bf16(a, b, c, 0, 0, 0);
}
// async global->LDS, 16B per lane; LDS dest = wave-uniform base + lane*16
__device__ __forceinline__ void load16_lds(const bf16* g, bf16* l) {
    __builtin_amdgcn_global_load_lds(
        (__attribute__((address_space(1))) void*)g,
        (__attribute__((address_space(3))) void*)l, 16, 0, 0);
}
// gelu(t) ~= t * sigmoid(2*0.79788456*(t + 0.044715 t^3)); max abs err ~3e-3
__device__ __forceinline__ float gelu_fast(float t) {
    const float u = t * (0.7978845608f + 0.0356774081f * t * t);
    return t * __builtin_amdgcn_rcpf(1.0f + exp2f(-2.8853900818f * u));
}

// ---------------------------------------------------------------------------
// LN body (row of 1024, fp32 in -> bf16 out), shared by fused & standalone.
// ---------------------------------------------------------------------------
__device__ __forceinline__ void ln_row(const float* __restrict__ xin,
                                       bf16* __restrict__ out, int row, int tid,
                                       const float* __restrict__ gamma,
                                       const float* __restrict__ beta,
                                       float* red) {
    const float4 f = *(const float4*)(xin + (size_t)row * 1024 + tid * 4);
    float v[4] = {f.x, f.y, f.z, f.w};
    float s = v[0] + v[1] + v[2] + v[3];
    float s2 = v[0] * v[0] + v[1] * v[1] + v[2] * v[2] + v[3] * v[3];
#pragma unroll
    for (int off = 1; off < 64; off <<= 1) {
        s += __shfl_xor(s, off);
        s2 += __shfl_xor(s2, off);
    }
    const int wave = tid >> 6, lane = tid & 63;
    if (lane == 0) { red[wave] = s; red[4 + wave] = s2; }
    __syncthreads();
    s = red[0] + red[1] + red[2] + red[3];
    s2 = red[4] + red[5] + red[6] + red[7];
    const float mean = s * (1.0f / 1024.0f);
    float var = s2 * (1.0f / 1024.0f) - mean * mean;
    var = fmaxf(var, 0.0f);
    const float rstd = 1.0f / (sqrtf(var) + 1e-6f);
    const int c = tid * 4;
    const float4 g = *(const float4*)(gamma + c);
    const float4 b = *(const float4*)(beta + c);
    bf16x4 o;
    o[0] = (bf16)((v[0] - mean) * rstd * g.x + b.x);
    o[1] = (bf16)((v[1] - mean) * rstd * g.y + b.y);
    o[2] = (bf16)((v[2] - mean) * rstd * g.z + b.z);
    o[3] = (bf16)((v[3] - mean) * rstd * g.w + b.w);
    *(bf16x4*)(out + (size_t)row * 1024 + c) = o;
}

// ---------------------------------------------------------------------------
// Fused: blocks [0,12288) convert all 4 weight tensors fp32->bf16;
// blocks [12288,16384) run LN1 on rows 0..4095. Independent data.
// ---------------------------------------------------------------------------
__global__ __launch_bounds__(256) void cvt4_ln_kernel(const float* __restrict__ s0,
                                                      const float* __restrict__ s1,
                                                      const float* __restrict__ s2,
                                                      const float* __restrict__ s3,
                                                      bf16* __restrict__ dst,
                                                      const float* __restrict__ xin,
                                                      bf16* __restrict__ hout,
                                                      const float* __restrict__ gamma,
                                                      const float* __restrict__ beta) {
    __shared__ float red[8];
    const int blk = blockIdx.x;
    const int tid = threadIdx.x;
    if (blk >= 12288) {
        ln_row(xin, hout, blk - 12288, tid, gamma, beta, red);
        return;
    }
    const float* s;
    int base;
    if (blk < 3072)      { s = s0; base = blk * 1024; }
    else if (blk < 4096) { s = s1; base = (blk - 3072) * 1024; }
    else if (blk < 8192) { s = s2; base = (blk - 4096) * 1024; }
    else                 { s = s3; base = (blk - 8192) * 1024; }
    const int t4 = tid * 4;
    const float4 f = *(const float4*)(s + base + t4);
    bf16x4 o;
    o[0] = (bf16)f.x; o[1] = (bf16)f.y; o[2] = (bf16)f.z; o[3] = (bf16)f.w;
    *(bf16x4*)(dst + (size_t)blk * 1024 + t4) = o;
}

// ---------------------------------------------------------------------------
// Standalone LN (LN2).
// ---------------------------------------------------------------------------
__global__ __launch_bounds__(256) void ln_kernel(const float* __restrict__ xin,
                                                 bf16* __restrict__ out,
                                                 const float* __restrict__ gamma,
                                                 const float* __restrict__ beta) {
    __shared__ float red[8];
    ln_row(xin, out, blockIdx.x, threadIdx.x, gamma, beta, red);
}

// ---------------------------------------------------------------------------
// gemm_r3w8: RING-3 LDS 128x128/BK=32, 8 waves (r10-verified: occ 41%,
// 0 conflicts, VGPR 40). Used for QKV (EPI 4) and FFN1 (EPI 2) where
// 48 KiB keeps 3 blocks/CU.
//   iter t: issue STAGE(t+2) -> ds_read/MFMA tile t -> vmcnt(2) -> s_barrier.
// XOR bank swizzle: staging (row, slot c) fetches global chunk
// c ^ ((row>>1)&3); readers fetch phys chunk quad ^ ((row>>1)&3).
// ---------------------------------------------------------------------------
#define STAGE(tt, bi)                                              \
    do {                                                           \
        const int _k0 = (tt) << 5;                                 \
        load16_lds(Ap + _k0, &As[bi][tid * 8]);                    \
        load16_lds(Bp + _k0, &Bs[bi][tid * 8]);                    \
    } while (0)

template <int EPI>
__global__ __launch_bounds__(512, 4) void gemm_r3w8(const bf16* __restrict__ A,
                                                    const bf16* __restrict__ B,
                                                    int N, int K, int ldk,
                                                    bf16* __restrict__ outb,
                                                    float* __restrict__ outf,
                                                    const float* __restrict__ bias,
                                                    const float* __restrict__ resf,
                                                    bf16* __restrict__ qk,
                                                    bf16* __restrict__ vt) {
    __shared__ alignas(16) bf16 As[3][128 * 32];
    __shared__ alignas(16) bf16 Bs[3][128 * 32];
    const int tid = threadIdx.x;
    const int bm = blockIdx.x, bn = blockIdx.y;
    const int wave = tid >> 6, lane = tid & 63;
    const int wm = (wave >> 2) * 64, wn = (wave & 3) * 32;   // 2M x 4N
    const int l16 = lane & 15, quad = lane >> 4;

    f32x4 acc[4][2] = {};

    const size_t koff = (size_t)blockIdx.z * K;
    const int row0 = tid >> 2, ch0 = tid & 3;        // 512 thr: 128 rows x 4 ch
    const int gch = ch0 ^ ((row0 >> 1) & 3);         // source-permuted chunk
    const bf16* Ap = A + (size_t)(bm * 128 + row0) * ldk + koff + gch * 8;
    const bf16* Bp = B + (size_t)(bn * 128 + row0) * ldk + koff + gch * 8;

    const int nt = K >> 5;

    STAGE(0, 0);
    STAGE(1, 1);
    asm volatile("s_waitcnt vmcnt(2)" ::: "memory");
    __builtin_amdgcn_s_barrier();
    asm volatile("" ::: "memory");

    int i0 = 0, i1 = 1, i2 = 2;
    for (int t = 0; t < nt; ++t) {
        if (t + 2 < nt) STAGE(t + 2, i2);

        bf16x8 af[4], bfr[2];
#pragma unroll
        for (int i = 0; i < 4; i++) {
            const int ra = wm + i * 16 + l16;
            af[i] = *(const bf16x8*)(&As[i0][ra * 32 + (quad ^ ((ra >> 1) & 3)) * 8]);
        }
#pragma unroll
        for (int j = 0; j < 2; j++) {
            const int rb = wn + j * 16 + l16;
            bfr[j] = *(const bf16x8*)(&Bs[i0][rb * 32 + (quad ^ ((rb >> 1) & 3)) * 8]);
        }
        __builtin_amdgcn_s_setprio(1);
#pragma unroll
        for (int i = 0; i < 4; i++)
#pragma unroll
            for (int j = 0; j < 2; j++) acc[i][j] = mfma16(af[i], bfr[j], acc[i][j]);
        __builtin_amdgcn_s_setprio(0);

        if (t + 2 < nt) {
            asm volatile("s_waitcnt vmcnt(2)" ::: "memory");
        } else if (t + 1 < nt) {
            asm volatile("s_waitcnt vmcnt(0)" ::: "memory");
        }
        if (t + 1 < nt) {
            __builtin_amdgcn_s_barrier();
            asm volatile("" ::: "memory");
        }
        const int tmp = i0; i0 = i1; i1 = i2; i2 = tmp;
    }

#pragma unroll
    for (int i = 0; i < 4; i++) {
#pragma unroll
        for (int j = 0; j < 2; j++) {
            const int gr0 = bm * 128 + wm + i * 16 + quad * 4;
            const int gc = bn * 128 + wn + j * 16 + l16;
            float bv = 0.0f;
            if (EPI == 2) bv = bias[gc];
            if (EPI == 4 && gc >= 2048) {
                const int n = gc - 2048;
                const int hh = n >> 6, dd = n & 63;
                const int bb = gr0 >> 11, ss = gr0 & 2047;
                bf16x4 pk;
#pragma unroll
                for (int r = 0; r < 4; r++) pk[r] = (bf16)acc[i][j][r];
                *(bf16x4*)(vt + ((size_t)((bb * 16 + hh) * 64 + dd)) * 2048 + ss) = pk;
            } else {
#pragma unroll
                for (int r = 0; r < 4; r++) {
                    const float v = acc[i][j][r];
                    const size_t idx = (size_t)(gr0 + r) * N + gc;
                    if (EPI == 1) {
                        outf[idx] = v + resf[idx];
                    } else if (EPI == 2) {
                        outb[idx] = (bf16)gelu_fast(v + bv);
                    } else {
                        qk[(size_t)(gr0 + r) * 2048 + gc] = (bf16)v;
                    }
                }
            }
        }
    }
}

// ---------------------------------------------------------------------------
// gemm_r4w8: RING-4 variant (64 KiB LDS, 2-iteration prefetch window).
// iter t: issue STAGE(t+3) -> compute tile t -> counted wait (4/2/0 ladder)
// -> s_barrier. Write-after-read: STAGE(t+3) targets the buffer of tile t-1,
// whose reads finished before iter t-1's closing barrier.
// Used for out-proj (EPI 1) and FFN2 (EPI 6) — both 1 block/CU.
// EPI 6: in-place accumulate x2 += v + bias (block-exclusive tiles; replaces
// split-K's 32 MB atomicAdd RMW stream).
// ---------------------------------------------------------------------------
template <int EPI>
__global__ __launch_bounds__(512, 2) void gemm_r4w8(const bf16* __restrict__ A,
                                                    const bf16* __restrict__ B,
                                                    int N, int K, int ldk,
                                                    bf16* __restrict__ outb,
                                                    float* __restrict__ outf,
                                                    const float* __restrict__ bias,
                                                    const float* __restrict__ resf,
                                                    bf16* __restrict__ qk,
                                                    bf16* __restrict__ vt) {
    __shared__ alignas(16) bf16 As[4][128 * 32];
    __shared__ alignas(16) bf16 Bs[4][128 * 32];
    const int tid = threadIdx.x;
    const int bm = blockIdx.x, bn = blockIdx.y;
    const int wave = tid >> 6, lane = tid & 63;
    const int wm = (wave >> 2) * 64, wn = (wave & 3) * 32;   // 2M x 4N
    const int l16 = lane & 15, quad = lane >> 4;

    f32x4 acc[4][2] = {};

    const int row0 = tid >> 2, ch0 = tid & 3;
    const int gch = ch0 ^ ((row0 >> 1) & 3);
    const bf16* Ap = A + (size_t)(bm * 128 + row0) * ldk + gch * 8;
    const bf16* Bp = B + (size_t)(bn * 128 + row0) * ldk + gch * 8;

    const int nt = K >> 5;                   // >= 4 for all users (32 / 128)

    STAGE(0, 0);
    STAGE(1, 1);
    STAGE(2, 2);
    asm volatile("s_waitcnt vmcnt(4)" ::: "memory");
    __builtin_amdgcn_s_barrier();
    asm volatile("" ::: "memory");

    int i0 = 0, i1 = 1, i2 = 2, i3 = 3;      // i0=compute, i3=stage dest
    for (int t = 0; t < nt; ++t) {
        if (t + 3 < nt) STAGE(t + 3, i3);

        bf16x8 af[4], bfr[2];
#pragma unroll
        for (int i = 0; i < 4; i++) {
            const int ra = wm + i * 16 + l16;
            af[i] = *(const bf16x8*)(&As[i0][ra * 32 + (quad ^ ((ra >> 1) & 3)) * 8]);
        }
#pragma unroll
        for (int j = 0; j < 2; j++) {
            const int rb = wn + j * 16 + l16;
            bfr[j] = *(const bf16x8*)(&Bs[i0][rb * 32 + (quad ^ ((rb >> 1) & 3)) * 8]);
        }
        __builtin_amdgcn_s_setprio(1);
#pragma unroll
        for (int i = 0; i < 4; i++)
#pragma unroll
            for (int j = 0; j < 2; j++) acc[i][j] = mfma16(af[i], bfr[j], acc[i][j]);
        __builtin_amdgcn_s_setprio(0);

        if (t + 3 < nt) {
            asm volatile("s_waitcnt vmcnt(4)" ::: "memory");
        } else if (t + 2 < nt) {
            asm volatile("s_waitcnt vmcnt(2)" ::: "memory");
        } else if (t + 1 < nt) {
            asm volatile("s_waitcnt vmcnt(0)" ::: "memory");
        }
        if (t + 1 < nt) {
            __builtin_amdgcn_s_barrier();
            asm volatile("" ::: "memory");
        }
        const int tmp = i0; i0 = i1; i1 = i2; i2 = i3; i3 = tmp;
    }

#pragma unroll
    for (int i = 0; i < 4; i++) {
#pragma unroll
        for (int j = 0; j < 2; j++) {
            const int gr0 = bm * 128 + wm + i * 16 + quad * 4;
            const int gc = bn * 128 + wn + j * 16 + l16;
            float bv = 0.0f;
            if (EPI == 6) bv = bias[gc];
#pragma unroll
            for (int r = 0; r < 4; r++) {
                const float v = acc[i][j][r];
                const size_t idx = (size_t)(gr0 + r) * N + gc;
                if (EPI == 1) {
                    outf[idx] = v + resf[idx];
                } else if (EPI == 6) {
                    outf[idx] += v + bv;      // block-exclusive in-place add
                } else {
                    outb[idx] = (bf16)v;
                }
            }
        }
    }
}
#undef STAGE

// ---------------------------------------------------------------------------
// Causal flash attention v3 — r5-exact body (verified ~55us).
// Fixed-shift softmax (shift=12; exact softmax, no online max/rescale).
// ---------------------------------------------------------------------------
__global__ __launch_bounds__(256, 4) void flash_attn(const bf16* __restrict__ qk,
                                                     const bf16* __restrict__ vt,
                                                     bf16* __restrict__ attn) {
    __shared__ alignas(16) bf16 Ks[64 * 72];
    __shared__ alignas(16) bf16 Vs[64 * 72];
    __shared__ alignas(16) bf16 Ps[4][16 * 72];
    const int tid = threadIdx.x;
    const int wave = tid >> 6, lane = tid & 63;
    const int l16 = lane & 15, quad = lane >> 4;
    const int bh = blockIdx.x;
    const int qt = 31 - blockIdx.y;
    const int b = bh >> 4, h = bh & 15;
    const int q0w = qt * 64 + wave * 16;
    const bf16* qkb = qk + (size_t)b * 2048 * 2048;
    const bf16* vtb = vt + (size_t)bh * 64 * 2048;

    bf16x8 qf[2];
#pragma unroll
    for (int c = 0; c < 2; c++) {
        bf16x8 v = *(const bf16x8*)(qkb + (size_t)(q0w + l16) * 2048 +
                                    h * 64 + c * 32 + quad * 8);
#pragma unroll
        for (int e = 0; e < 8; e++) v[e] = (bf16)((float)v[e] * 0.125f);
        qf[c] = v;
    }

    float lsum[4] = {0.0f, 0.0f, 0.0f, 0.0f};
    f32x4 o[4] = {};

    const int ntiles = qt + 1;
    for (int t = 0; t < ntiles; t++) {
        const int k0 = t * 64;
#pragma unroll
        for (int i = 0; i < 2; i++) {
            const int r = i * 32 + (tid >> 3), ch = tid & 7;
            *(uint4*)(&Ks[r * 72 + ch * 8]) =
                *(const uint4*)(qkb + (size_t)(k0 + r) * 2048 + 1024 + h * 64 + ch * 8);
            *(uint4*)(&Vs[r * 72 + ch * 8]) =
                *(const uint4*)(vtb + (size_t)r * 2048 + k0 + ch * 8);
        }
        __syncthreads();
        f32x4 s[4];
        __builtin_amdgcn_s_setprio(1);
#pragma unroll
        for (int kt = 0; kt < 4; kt++) {
            const bf16x8 k0f = *(const bf16x8*)(&Ks[(kt * 16 + l16) * 72 + quad * 8]);
            const bf16x8 k1f = *(const bf16x8*)(&Ks[(kt * 16 + l16) * 72 + 32 + quad * 8]);
            s[kt] = mfma16(qf[1], k1f, mfma16(qf[0], k0f, (f32x4){0, 0, 0, 0}));
        }
        __builtin_amdgcn_s_setprio(0);
        const bool need_mask = (t == ntiles - 1);
#pragma unroll
        for (int r = 0; r < 4; r++) {
            const int qrow = q0w + quad * 4 + r;
            float e0 = exp2f(fmaf(s[0][r], LOG2E, NSHIFT));
            float e1 = exp2f(fmaf(s[1][r], LOG2E, NSHIFT));
            float e2 = exp2f(fmaf(s[2][r], LOG2E, NSHIFT));
            float e3 = exp2f(fmaf(s[3][r], LOG2E, NSHIFT));
            if (need_mask) {
                if (k0 + l16 > qrow) e0 = 0.0f;
                if (k0 + 16 + l16 > qrow) e1 = 0.0f;
                if (k0 + 32 + l16 > qrow) e2 = 0.0f;
                if (k0 + 48 + l16 > qrow) e3 = 0.0f;
            }
            lsum[r] += (e0 + e1) + (e2 + e3);
            bf16* pp = &Ps[wave][(quad * 4 + r) * 72];
            pp[l16] = (bf16)e0;
            pp[16 + l16] = (bf16)e1;
            pp[32 + l16] = (bf16)e2;
            pp[48 + l16] = (bf16)e3;
        }
        // PV (Ps is per-wave private; lgkmcnt handles write->read in-wave)
        __builtin_amdgcn_s_setprio(1);
#pragma unroll
        for (int c = 0; c < 2; c++) {
            const bf16x8 pf = *(const bf16x8*)(&Ps[wave][l16 * 72 + c * 32 + quad * 8]);
#pragma unroll
            for (int dt = 0; dt < 4; dt++) {
                const bf16x8 vf =
                    *(const bf16x8*)(&Vs[(dt * 16 + l16) * 72 + c * 32 + quad * 8]);
                o[dt] = mfma16(pf, vf, o[dt]);
            }
        }
        __builtin_amdgcn_s_setprio(0);
        __syncthreads();
    }

    // epilogue: reduce l over the 16 lanes of each quad (bits 0-3)
#pragma unroll
    for (int r = 0; r < 4; r++) {
#pragma unroll
        for (int off = 1; off < 16; off <<= 1) lsum[r] += __shfl_xor(lsum[r], off);
        lsum[r] = 1.0f / fmaxf(lsum[r], 1e-30f);
    }
    bf16* ob = attn + (size_t)b * 2048 * 1024;
#pragma unroll
    for (int dt = 0; dt < 4; dt++)
#pragma unroll
        for (int r = 0; r < 4; r++) {
            const int q = q0w + quad * 4 + r;
            ob[(size_t)q * 1024 + h * 64 + dt * 16 + l16] = (bf16)(o[dt][r] * lsum[r]);
        }
}

// ---------------------------------------------------------------------------
extern "C" void kernel_launch(void* const* d_in, const int* in_sizes, int n_in,
                              void* d_out, int out_size, void* d_ws, size_t ws_size,
                              hipStream_t stream) {
    const float* x    = (const float*)d_in[0];
    const float* Wqkv = (const float*)d_in[2];
    const float* Wout = (const float*)d_in[3];
    const float* W1   = (const float*)d_in[4];
    const float* b1   = (const float*)d_in[5];
    const float* W2   = (const float*)d_in[6];
    const float* b2   = (const float*)d_in[7];
    const float* g1   = (const float*)d_in[8];
    const float* be1  = (const float*)d_in[9];
    const float* g2   = (const float*)d_in[10];
    const float* be2  = (const float*)d_in[11];

    char* ws = (char*)d_ws;
    bf16* Wb     = (bf16*)(ws);                 // all 4 weights, contiguous 24 MiB
    bf16* Wqkv_b = (bf16*)(ws);
    bf16* Wout_b = (bf16*)(ws + (6u << 20));
    bf16* W1_b   = (bf16*)(ws + (8u << 20));
    bf16* W2_b   = (bf16*)(ws + (16u << 20));
    bf16* h      = (bf16*)(ws + (24u << 20));
    bf16* qkbuf  = (bf16*)(ws + (32u << 20));
    bf16* vtbuf  = (bf16*)(ws + (48u << 20));
    bf16* attn   = (bf16*)(ws + (56u << 20));
    bf16* act    = (bf16*)(ws + (32u << 20));   // aliases qk/vt/attn post-attention
    float* x2    = (float*)d_out;               // residual stream lives in d_out

    // 0+1) weights fp32->bf16 AND h = LN1(x), one launch
    cvt4_ln_kernel<<<16384, 256, 0, stream>>>(Wqkv, Wout, W1, W2, Wb,
                                              x, h, g1, be1);
    // 2) qkv = h @ Wqkv^T -> qk rows + V^T   (ring-3, 8 waves)
    gemm_r3w8<4><<<dim3(32, 24), 512, 0, stream>>>(h, Wqkv_b, 3072, 1024, 1024,
                                                   nullptr, nullptr, nullptr, nullptr,
                                                   qkbuf, vtbuf);
    // 3) attn = causal_flash(qk, vt)   (r5-exact)
    flash_attn<<<dim3(32, 32), 256, 0, stream>>>(qkbuf, vtbuf, attn);
    // 4) x2 = attn @ Wout^T + x   (ring-4, 8 waves; 1 block/CU, deep window)
    gemm_r4w8<1><<<dim3(32, 8), 512, 0, stream>>>(attn, Wout_b, 1024, 1024, 1024,
                                                  nullptr, x2, nullptr, x, nullptr, nullptr);
    // 5) h = LN2(x2)
    ln_kernel<<<4096, 256, 0, stream>>>(x2, h, g2, be2);
    // 6) act = gelu_fast(h @ W1^T + b1)   (ring-3, 8 waves)
    gemm_r3w8<2><<<dim3(32, 32), 512, 0, stream>>>(h, W1_b, 4096, 1024, 1024,
                                                   act, nullptr, b1, nullptr, nullptr, nullptr);
    // 7) x2 += act @ W2^T + b2   (ring-4, NO split-K, in-place EPI 6)
    gemm_r4w8<6><<<dim3(32, 8), 512, 0, stream>>>(act, W2_b, 1024, 4096, 4096,
                                                  nullptr, x2, b2, nullptr, nullptr, nullptr);
}